// Round 9
// baseline (622.677 us; speedup 1.0000x reference)
//
#include <hip/hip_runtime.h>

// LightGCN: N=U+I nodes, D=64 features, E edges (symmetrized to 2E directed).
// CSR built per call via bucket sort (256-row buckets). Rows PADDED to
// multiples of 8 with sentinel zero-row N -> branch-free SpMM.
// x stored pre-scaled: xs[c] = dis[c]*x[c] (bf16x2 packed, row = 128B):
// S = sum xs[c]; x_new = dr*S; xs_next = dr^2*S.
// R8: NO fdot2_f32_bf16 (wrong results on gfx950).
// R9 (REVERTED): row-per-octet spmm. R7 phase-split wave-per-row stays.
// R10: spmm BYTES-bound at ~3.5 TB/s TCC plateau; f32 acc RMW eliminated.
// R11 (REVERTED): range-sorted cols -> no orderable locality, FETCH flat.
// R12/R13 (REVERTED): global-atomic histogram = 318us, WRITE 249MB (~31B/
// atomic, serviced at cross-XCD coherence point). Histogram in LDS only.
// R14: 587.6us. csr_build full-bucket LDS staging (pairs 2x); TILE 4096.
// R15: prebuild ~275us vs ~160MB logical -> attack identified write-amp:
//  - bucket_scatter TILE 16384, two-phase (histogram rows-only re-read ->
//    scan -> re-read edges + LDS stage -> coalesced flush, runs ~112B).
//    Kills the 28B-run scattered stores (~2-3x write amplification).
//  - csr_build stages RAW bucket in LDS once (RAW_CAP 14592 = +8sigma;
//    padded total provably <= FULL_CAP) -> pairs read 1x (was 2x).
// spmm kernels byte-identical (tripwire: spmm_last 118us / FETCH 376MB).

static constexpr int D = 64;
#define BSHIFT 8
#define BROWS 256               // rows per bucket
#define KP 1024                 // padded bucket count for scans (>= KB=586)
#define TILE 16384              // entries per bucket_scatter block
#define PADSLACK (7 * BROWS)    // max pad growth per bucket (rows pad to x8)
#define RAW_CAP 14592           // raw bucket staging (58.4KB; +8sigma, and
                                // RAW_CAP + 1792 <= FULL_CAP)
#define FULL_CAP 16384          // sorted bucket staging (64 KB LDS)
#define COLS_SLACK 8192         // safe over-read slack for spmm col loads

__device__ __forceinline__ float bflo(unsigned v) {
    unsigned u = v << 16;
    return __builtin_bit_cast(float, u);
}
__device__ __forceinline__ float bfhi(unsigned v) {
    unsigned u = v & 0xFFFF0000u;
    return __builtin_bit_cast(float, u);
}
__device__ __forceinline__ unsigned pack_bf16x2(float a, float b) {
    unsigned ua = __builtin_bit_cast(unsigned, a);
    unsigned ub = __builtin_bit_cast(unsigned, b);
    ua += 0x7FFFu + ((ua >> 16) & 1u);   // RNE
    ub += 0x7FFFu + ((ub >> 16) & 1u);
    return (ua >> 16) | (ub & 0xFFFF0000u);
}
// f16 pack/unpack for the x_l recovery arrays (RNE via _Float16 cast).
__device__ __forceinline__ unsigned pack_f16x2(float a, float b) {
    unsigned short ua = __builtin_bit_cast(unsigned short, (_Float16)a);
    unsigned short ub = __builtin_bit_cast(unsigned short, (_Float16)b);
    return (unsigned)ua | ((unsigned)ub << 16);
}
__device__ __forceinline__ float f16lo(unsigned v) {
    return (float)__builtin_bit_cast(_Float16, (unsigned short)(v & 0xFFFFu));
}
__device__ __forceinline__ float f16hi(unsigned v) {
    return (float)__builtin_bit_cast(_Float16, (unsigned short)(v >> 16));
}

// bf16x2 pair accumulate: se += lo, so += hi. Exact f32 adds.
__device__ __forceinline__ void acc_bf2(unsigned u, float& se, float& so) {
    se += bflo(u);
    so += bfhi(u);
}

// ---- Pass 0: per-bucket histogram (LDS only; int4-vectorized edge reads) ----
__global__ __launch_bounds__(256) void bucket_count(
        const int* __restrict__ eu, const int* __restrict__ ei,
        int* __restrict__ bcnt, int E, int U) {
    __shared__ int h[KP];
    int tid = threadIdx.x;
#pragma unroll
    for (int k = 0; k < 4; ++k) h[tid + k * 256] = 0;
    __syncthreads();
    int E4 = E >> 2;
    int stride = gridDim.x * blockDim.x;
    int g = blockIdx.x * blockDim.x + tid;
    const int4* eu4 = (const int4*)eu;
    const int4* ei4 = (const int4*)ei;
    for (int e = g; e < E4; e += stride) {
        int4 u = eu4[e];
        int4 it = ei4[e];
        atomicAdd(&h[u.x >> BSHIFT], 1);
        atomicAdd(&h[u.y >> BSHIFT], 1);
        atomicAdd(&h[u.z >> BSHIFT], 1);
        atomicAdd(&h[u.w >> BSHIFT], 1);
        atomicAdd(&h[(U + it.x) >> BSHIFT], 1);
        atomicAdd(&h[(U + it.y) >> BSHIFT], 1);
        atomicAdd(&h[(U + it.z) >> BSHIFT], 1);
        atomicAdd(&h[(U + it.w) >> BSHIFT], 1);
    }
    if (blockIdx.x == 0 && tid < (E - (E4 << 2))) {   // tail (<4 edges)
        int e = (E4 << 2) + tid;
        atomicAdd(&h[eu[e] >> BSHIFT], 1);
        atomicAdd(&h[(U + ei[e]) >> BSHIFT], 1);
    }
    __syncthreads();
#pragma unroll
    for (int k = 0; k < 4; ++k) {
        int v = h[tid + k * 256];
        if (v) atomicAdd(&bcnt[tid + k * 256], v);
    }
}

// ---- Pass 1: scan bucket counts -> bucket bases + global cursors ----
__global__ void bscan(const int* __restrict__ bcnt, int* __restrict__ bbase,
                      int* __restrict__ bcursor, int KB, int twoE) {
    __shared__ int s[KP];
    int tid = threadIdx.x; // 1024 threads, 1 block
    int v = (tid < KB) ? bcnt[tid] : 0;
    s[tid] = v;
    __syncthreads();
    for (int off = 1; off < KP; off <<= 1) {
        int a = (tid >= off) ? s[tid - off] : 0;
        __syncthreads();
        s[tid] += a;
        __syncthreads();
    }
    int ex = s[tid] - v; // exclusive
    if (tid < KB) { bbase[tid] = ex; bcursor[tid] = ex; }
    if (tid == KB) bbase[tid] = twoE;
    if (tid > KB) bcursor[tid] = 0;
}

// ---- Pass 2: scatter entries into bucket-grouped pairs buffer ----
// packed entry: (row & 255) << 18 | col   (col < 2^18)
// R15: TILE 16384, two-phase. Phase 1 reads ONLY the row source (16MB) and
// histograms; after scan+reserve, phase 2 re-reads edges, stages into 64KB
// LDS; flush writes runs of ~28 entries (112B) -- line-efficient vs the old
// 7-entry (28B) scattered runs.
__global__ __launch_bounds__(256) void bucket_scatter(
        const int* __restrict__ eu, const int* __restrict__ ei,
        int* __restrict__ bcursor, unsigned* __restrict__ pairs,
        int E, int U, int twoE) {
    __shared__ int hist[KP];           // counts -> local running cursor
    __shared__ int sbase[KP];          // tile-local exclusive base
    __shared__ int gbase[KP];          // reserved global base
    __shared__ unsigned staging[TILE];
    __shared__ unsigned short sb[TILE];
    int tid = threadIdx.x;
#pragma unroll
    for (int k = 0; k < 4; ++k) hist[tid + k * 256] = 0;
    __syncthreads();
    int base_e = blockIdx.x * TILE;
    int tile_n = min(TILE, twoE - base_e);
    // phase 1: histogram (row source only)
    for (int j = tid; j < tile_n; j += 256) {
        int e = base_e + j;
        int r = (e < E) ? eu[e] : (U + ei[e - E]);
        atomicAdd(&hist[r >> BSHIFT], 1);
    }
    __syncthreads();
    int cc[4];
#pragma unroll
    for (int k = 0; k < 4; ++k) cc[k] = hist[tid + k * 256];
    for (int off = 1; off < KP; off <<= 1) {
        int a[4];
#pragma unroll
        for (int k = 0; k < 4; ++k) {
            int idx = tid + k * 256;
            a[k] = (idx >= off) ? hist[idx - off] : 0;
        }
        __syncthreads();
#pragma unroll
        for (int k = 0; k < 4; ++k) hist[tid + k * 256] += a[k];
        __syncthreads();
    }
#pragma unroll
    for (int k = 0; k < 4; ++k) {
        int idx = tid + k * 256;
        int e0 = hist[idx] - cc[k];
        sbase[idx] = e0;
        if (cc[k] > 0) gbase[idx] = atomicAdd(&bcursor[idx], cc[k]);
        hist[idx] = e0;     // own-slot overwrite -> running cursor
    }
    __syncthreads();
    // phase 2: re-read edges, stage into LDS
    for (int j = tid; j < tile_n; j += 256) {
        int e = base_e + j;
        int r, c;
        if (e < E) { r = eu[e]; c = U + ei[e]; }
        else       { c = eu[e - E]; r = U + ei[e - E]; }
        int b = r >> BSHIFT;
        int pos = atomicAdd(&hist[b], 1);
        staging[pos] = ((unsigned)(r & (BROWS - 1)) << 18) | (unsigned)c;
        sb[pos] = (unsigned short)b;
    }
    __syncthreads();
    // flush: coalesced, long per-bucket runs
    for (int j = tid; j < tile_n; j += 256) {
        int b = sb[j];
        pairs[gbase[b] + (j - sbase[b])] = staging[j];
    }
}

// ---- Pass 3: per-bucket counting sort -> deg/row_ptr/dis/cols ----
// 256 threads, one thread per row. Padded base = bbase[b] + 1792*b.
// R15: raw bucket staged in LDS ONCE (read 1 of pairs); histogram and
// scatter both read LDS. RAW_CAP chosen so padded total <= FULL_CAP when
// raw fits. Fallbacks: global re-read staging, then global scatter.
__global__ __launch_bounds__(256) void csr_build(
        const unsigned* __restrict__ pairs, const int* __restrict__ bbase,
        int* __restrict__ deg, int* __restrict__ row_ptr,
        float* __restrict__ dis, int* __restrict__ cols, int N) {
    __shared__ int cnt[BROWS];
    __shared__ int cur[BROWS];
    __shared__ unsigned raw[RAW_CAP];
    __shared__ int lbuf[FULL_CAP];
    int tid = threadIdx.x;
    int b = blockIdx.x;
    int lo = bbase[b], hi = bbase[b + 1];
    int cbase = lo + PADSLACK * b;
    int nraw = hi - lo;
    bool fits = (nraw <= RAW_CAP);       // block-uniform
    cnt[tid] = 0;
    __syncthreads();
    if (fits) {
        for (int i = tid; i < nraw; i += 256) raw[i] = pairs[lo + i];
        __syncthreads();
        for (int i = tid; i < nraw; i += 256)
            atomicAdd(&cnt[raw[i] >> 18], 1);
    } else {
        for (int i = lo + tid; i < hi; i += 256)
            atomicAdd(&cnt[pairs[i] >> 18], 1);
    }
    __syncthreads();
    int c = cnt[tid];
    int p = (c + 7) & ~7;
    cnt[tid] = p;                        // own-slot overwrite, no cross reads
    __syncthreads();
    for (int off = 1; off < BROWS; off <<= 1) {
        int a = (tid >= off) ? cnt[tid - off] : 0;
        __syncthreads();
        cnt[tid] += a;
        __syncthreads();
    }
    int e = cnt[tid] - p; // exclusive padded offset within bucket
    int r = (b << BSHIFT) + tid;
    if (r < N) {
        deg[r] = c;
        row_ptr[r] = cbase + e;
        dis[r] = rsqrtf((float)c + 1e-7f);
    }
    cur[tid] = e;
    int total = cnt[BROWS - 1];          // padded bucket total (block-uniform)
    __syncthreads();                     // cur[] visible before scatter
    if (fits) {                          // implies total <= FULL_CAP
        for (int i = tid; i < nraw; i += 256) {
            unsigned pe = raw[i];
            int pos = atomicAdd(&cur[pe >> 18], 1);
            lbuf[pos] = (int)(pe & 0x3FFFFu);
        }
        __syncthreads();
        for (int i = e + c; i < e + p; ++i) lbuf[i] = N;   // sentinel pad
        __syncthreads();
        for (int i = tid; i < total; i += 256)             // coalesced flush
            cols[cbase + i] = lbuf[i];
    } else if (total <= FULL_CAP) {
        for (int i = lo + tid; i < hi; i += 256) {
            unsigned pe = pairs[i];
            int pos = atomicAdd(&cur[pe >> 18], 1);
            lbuf[pos] = (int)(pe & 0x3FFFFu);
        }
        __syncthreads();
        for (int i = e + c; i < e + p; ++i) lbuf[i] = N;
        __syncthreads();
        for (int i = tid; i < total; i += 256)
            cols[cbase + i] = lbuf[i];
    } else {
        // fallback: direct global scatter (pathological bucket size)
        for (int i = lo + tid; i < hi; i += 256) {
            unsigned pe = pairs[i];
            int pos = atomicAdd(&cur[pe >> 18], 1);
            cols[cbase + pos] = (int)(pe & 0x3FFFFu);
        }
        __syncthreads();
        for (int i = e + c; i < e + p; ++i) cols[cbase + i] = N;
    }
}

// init: writes xs0 (bf16 pre-scaled) + sentinel zero-rows of BOTH xs buffers.
// NO acc write (out is produced once, by spmm_last).
__global__ __launch_bounds__(256) void init_kernel(
        const float4* __restrict__ ue4, const float4* __restrict__ ie4,
        const float* __restrict__ dis,
        uint4* __restrict__ xsA4, uint4* __restrict__ xsB4,
        int U8, int N8) {
    int t = blockIdx.x * blockDim.x + threadIdx.x;
    if (t >= N8 + 8) return;
    if (t >= N8) {                        // sentinel zero-row N (both buffers)
        uint4 z = {0u, 0u, 0u, 0u};
        xsA4[t] = z;
        xsB4[t] = z;
        return;
    }
    float dv = dis[t >> 3];
    const float4* src = (t < U8) ? (ue4 + 2 * t) : (ie4 + 2 * (t - U8));
    float4 a0 = src[0];
    float4 a1 = src[1];
    uint4 w;
    w.x = pack_bf16x2(dv * a0.x, dv * a0.y);
    w.y = pack_bf16x2(dv * a0.z, dv * a0.w);
    w.z = pack_bf16x2(dv * a1.x, dv * a1.y);
    w.w = pack_bf16x2(dv * a1.z, dv * a1.w);
    xsA4[t] = w;
}

// One wave per row. lane = (n8 = lane>>3 neighbor slot, dp = lane&7 uint4 idx).
// One uint4 load covers 8 neighbor rows per instruction; one ds_bpermute per
// octet broadcasts the 8 cols. Rows padded to x8 with sentinel -> no tail code.
// Phase-split body: all bpermutes, then all gathers (up to 8 in flight), then
// accumulate. Layers 0/1: write xs_next + xh (f16 x_l copy) -- no f32 acc RMW.
__global__ __launch_bounds__(256) void spmm_mid(
        const int* __restrict__ row_ptr, const int* __restrict__ deg,
        const float* __restrict__ dis, const int* __restrict__ cols,
        const unsigned* __restrict__ xs, unsigned* __restrict__ xs_next,
        unsigned* __restrict__ xh, int N) {
    int wid = blockIdx.x * 4 + (threadIdx.x >> 6);
    if (wid >= N) return;
    int lane = threadIdx.x & 63;
    int n8 = lane >> 3;
    int dp = lane & 7;
    int start = row_ptr[wid];
    int cntp = (deg[wid] + 7) & ~7;
    float dr = dis[wid];
    const int* colp = cols + start;
    int vbase = n8 << 2;       // bpermute byte addr component
    int dpo = dp << 2;         // dword offset within row (uint4 = 4 dwords)
    float s0 = 0.f, s1 = 0.f, s2 = 0.f, s3 = 0.f;
    float s4 = 0.f, s5 = 0.f, s6 = 0.f, s7 = 0.f;
    for (int chunk = 0; chunk < cntp; chunk += 64) {
        int cv = colp[chunk + lane];           // over-read OK (slack at end)
        int nq = min(64, cntp - chunk) >> 3;
        nq = __builtin_amdgcn_readfirstlane(nq);   // wave-uniform -> SGPR branch
        int coq[8];
        uint4 vq[8];
#pragma unroll
        for (int q = 0; q < 8; ++q) {
            if (q < nq)
                coq[q] = __builtin_amdgcn_ds_bpermute((q << 5) + vbase, cv);
        }
#pragma unroll
        for (int q = 0; q < 8; ++q) {
            if (q < nq)
                vq[q] = *(const uint4*)(xs + (((unsigned)coq[q]) << 5) + dpo);
        }
#pragma unroll
        for (int q = 0; q < 8; ++q) {
            if (q < nq) {
                acc_bf2(vq[q].x, s0, s1);
                acc_bf2(vq[q].y, s2, s3);
                acc_bf2(vq[q].z, s4, s5);
                acc_bf2(vq[q].w, s6, s7);
            }
        }
    }
#pragma unroll
    for (int m = 8; m < 64; m <<= 1) {
        s0 += __shfl_xor(s0, m); s1 += __shfl_xor(s1, m);
        s2 += __shfl_xor(s2, m); s3 += __shfl_xor(s3, m);
        s4 += __shfl_xor(s4, m); s5 += __shfl_xor(s5, m);
        s6 += __shfl_xor(s6, m); s7 += __shfl_xor(s7, m);
    }
    if (n8 == 0) {
        float x0 = dr * s0, x1 = dr * s1, x2 = dr * s2, x3 = dr * s3;
        float x4 = dr * s4, x5 = dr * s5, x6 = dr * s6, x7 = dr * s7;
        uint4 w;
        w.x = pack_bf16x2(dr * x0, dr * x1);   // xs_next = dr^2 * S
        w.y = pack_bf16x2(dr * x2, dr * x3);
        w.z = pack_bf16x2(dr * x4, dr * x5);
        w.w = pack_bf16x2(dr * x6, dr * x7);
        ((uint4*)xs_next)[(wid << 3) + dp] = w;
        uint4 h;
        h.x = pack_f16x2(x0, x1);              // xh = x_l (f16, for final sum)
        h.y = pack_f16x2(x2, x3);
        h.z = pack_f16x2(x4, x5);
        h.w = pack_f16x2(x6, x7);
        ((uint4*)xh)[(wid << 3) + dp] = h;
    }
}

// Layer 2: gathers from xs2, then out = 0.25*(emb + x1 + x2 + x3).
// x1/x2 come from the f16 recovery arrays; emb re-read from inputs (f32).
__global__ __launch_bounds__(256) void spmm_last(
        const int* __restrict__ row_ptr, const int* __restrict__ deg,
        const float* __restrict__ dis, const int* __restrict__ cols,
        const unsigned* __restrict__ xs,
        const float4* __restrict__ ue4, const float4* __restrict__ ie4,
        const unsigned* __restrict__ xh1, const unsigned* __restrict__ xh2,
        float4* __restrict__ out4, int U, int N) {
    int wid = blockIdx.x * 4 + (threadIdx.x >> 6);
    if (wid >= N) return;
    int lane = threadIdx.x & 63;
    int n8 = lane >> 3;
    int dp = lane & 7;
    int start = row_ptr[wid];
    int cntp = (deg[wid] + 7) & ~7;
    float dr = dis[wid];
    const int* colp = cols + start;
    int vbase = n8 << 2;
    int dpo = dp << 2;
    float s0 = 0.f, s1 = 0.f, s2 = 0.f, s3 = 0.f;
    float s4 = 0.f, s5 = 0.f, s6 = 0.f, s7 = 0.f;
    for (int chunk = 0; chunk < cntp; chunk += 64) {
        int cv = colp[chunk + lane];
        int nq = min(64, cntp - chunk) >> 3;
        nq = __builtin_amdgcn_readfirstlane(nq);
        int coq[8];
        uint4 vq[8];
#pragma unroll
        for (int q = 0; q < 8; ++q) {
            if (q < nq)
                coq[q] = __builtin_amdgcn_ds_bpermute((q << 5) + vbase, cv);
        }
#pragma unroll
        for (int q = 0; q < 8; ++q) {
            if (q < nq)
                vq[q] = *(const uint4*)(xs + (((unsigned)coq[q]) << 5) + dpo);
        }
#pragma unroll
        for (int q = 0; q < 8; ++q) {
            if (q < nq) {
                acc_bf2(vq[q].x, s0, s1);
                acc_bf2(vq[q].y, s2, s3);
                acc_bf2(vq[q].z, s4, s5);
                acc_bf2(vq[q].w, s6, s7);
            }
        }
    }
#pragma unroll
    for (int m = 8; m < 64; m <<= 1) {
        s0 += __shfl_xor(s0, m); s1 += __shfl_xor(s1, m);
        s2 += __shfl_xor(s2, m); s3 += __shfl_xor(s3, m);
        s4 += __shfl_xor(s4, m); s5 += __shfl_xor(s5, m);
        s6 += __shfl_xor(s6, m); s7 += __shfl_xor(s7, m);
    }
    if (n8 == 0) {
        float x30 = dr * s0, x31 = dr * s1, x32 = dr * s2, x33 = dr * s3;
        float x34 = dr * s4, x35 = dr * s5, x36 = dr * s6, x37 = dr * s7;
        const float4* ep = (wid < U) ? (ue4 + (size_t)wid * 16)
                                     : (ie4 + (size_t)(wid - U) * 16);
        float4 e0 = ep[2 * dp];
        float4 e1 = ep[2 * dp + 1];
        uint4 h1 = ((const uint4*)xh1)[(wid << 3) + dp];
        uint4 h2 = ((const uint4*)xh2)[(wid << 3) + dp];
        float4 o0, o1;
        o0.x = 0.25f * (e0.x + f16lo(h1.x) + f16lo(h2.x) + x30);
        o0.y = 0.25f * (e0.y + f16hi(h1.x) + f16hi(h2.x) + x31);
        o0.z = 0.25f * (e0.z + f16lo(h1.y) + f16lo(h2.y) + x32);
        o0.w = 0.25f * (e0.w + f16hi(h1.y) + f16hi(h2.y) + x33);
        o1.x = 0.25f * (e1.x + f16lo(h1.z) + f16lo(h2.z) + x34);
        o1.y = 0.25f * (e1.y + f16hi(h1.z) + f16hi(h2.z) + x35);
        o1.z = 0.25f * (e1.z + f16lo(h1.w) + f16lo(h2.w) + x36);
        o1.w = 0.25f * (e1.w + f16hi(h1.w) + f16hi(h2.w) + x37);
        int oo = (wid << 4) + (dp << 1);
        out4[oo] = o0;
        out4[oo + 1] = o1;
    }
}

extern "C" void kernel_launch(void* const* d_in, const int* in_sizes, int n_in,
                              void* d_out, int out_size, void* d_ws, size_t ws_size,
                              hipStream_t stream) {
    const float* ue = (const float*)d_in[0];
    const float* ie = (const float*)d_in[1];
    const int* eu = (const int*)d_in[2];
    const int* ei = (const int*)d_in[3];
    const int U = in_sizes[0] / D; // 100001
    const int I = in_sizes[1] / D; // 50001
    const int N = U + I;           // 150002
    const int E = in_sizes[2];     // 4,000,000
    const int twoE = 2 * E;
    const int KB = (N + BROWS - 1) / BROWS; // 586
    float* out = (float*)d_out;

    char* ws = (char*)d_ws;
    auto alloc = [&](size_t bytes) {
        char* p = ws;
        ws += (bytes + 255) & ~(size_t)255;
        return p;
    };
    int* deg = (int*)alloc((size_t)N * 4);
    int* row_ptr = (int*)alloc((size_t)N * 4);
    float* dis = (float*)alloc((size_t)N * 4);
    int* bcnt = (int*)alloc(KP * 4);
    int* bbase = (int*)alloc((KP + 1) * 4);
    int* bcursor = (int*)alloc(KP * 4);
    int* cols = (int*)alloc(((size_t)twoE + (size_t)PADSLACK * (KB + 1) + COLS_SLACK) * 4);
    unsigned* pairs = (unsigned*)alloc((size_t)twoE * 4);       // 32 MB
    unsigned* xsA = (unsigned*)alloc(((size_t)N + 1) * 32 * 4); // bf16x2, +sentinel row
    unsigned* xsB = (unsigned*)alloc(((size_t)N + 1) * 32 * 4);
    // xh1 aliases `pairs` (dead after csr_build; 19.2MB <= 32MB). xh2 fresh.
    unsigned* xh1 = pairs;
    unsigned* xh2 = (unsigned*)alloc((size_t)N * 32 * 4);

    hipMemsetAsync(bcnt, 0, KP * 4, stream);
    bucket_count<<<1024, 256, 0, stream>>>(eu, ei, bcnt, E, U);
    bscan<<<1, KP, 0, stream>>>(bcnt, bbase, bcursor, KB, twoE);
    bucket_scatter<<<(twoE + TILE - 1) / TILE, 256, 0, stream>>>(
        eu, ei, bcursor, pairs, E, U, twoE);
    csr_build<<<KB, BROWS, 0, stream>>>(pairs, bbase, deg, row_ptr, dis, cols, N);

    int N8 = N * 8, U8 = U * 8;
    init_kernel<<<(N8 + 8 + 255) / 256, 256, 0, stream>>>(
        (const float4*)ue, (const float4*)ie, dis,
        (uint4*)xsA, (uint4*)xsB, U8, N8);

    int nblocks = (N + 3) / 4;
    // layer 0: xs0(A) -> xs1(B), xh1 = x1 (f16)
    spmm_mid<<<nblocks, 256, 0, stream>>>(
        row_ptr, deg, dis, cols, xsA, xsB, xh1, N);
    // layer 1: xs1(B) -> xs2(A; A is dead, sentinel intact), xh2 = x2 (f16)
    spmm_mid<<<nblocks, 256, 0, stream>>>(
        row_ptr, deg, dis, cols, xsB, xsA, xh2, N);
    // layer 2: gather xs2(A); out = 0.25*(emb + x1 + x2 + x3)
    spmm_last<<<nblocks, 256, 0, stream>>>(
        row_ptr, deg, dis, cols, xsA,
        (const float4*)ue, (const float4*)ie, xh1, xh2, (float4*)out, U, N);
}

// Round 10
// 596.822 us; speedup vs baseline: 1.0433x; 1.0433x over previous
//
#include <hip/hip_runtime.h>

// LightGCN: N=U+I nodes, D=64 features, E edges (symmetrized to 2E directed).
// CSR built per call via bucket sort (256-row buckets). Rows PADDED to
// multiples of 8 with sentinel zero-row N -> branch-free SpMM.
// x stored pre-scaled: xs[c] = dis[c]*x[c] (bf16x2 packed, row = 128B):
// S = sum xs[c]; x_new = dr*S; xs_next = dr^2*S.
// R8: NO fdot2_f32_bf16 (wrong results on gfx950).
// R9 (REVERTED): row-per-octet spmm. R7 phase-split wave-per-row stays.
// R10: spmm BYTES-bound at ~3.5 TB/s TCC plateau; f32 acc RMW eliminated.
// R11 (REVERTED): range-sorted cols -> no orderable locality.
// R12/R13 (REVERTED): global-atomic histogram: scattered device-scope
// atomics ~31B line-RMW each at the cross-XCD coherence point.
// R14: 587.6us. TILE-4096 register-staged scatter; csr_build 64KB staging.
// R15 (REVERTED): TILE 16384 + csr raw-staging spent occupancy (4->1 and
// 2->1 blocks/CU) to save bytes -> +35us. Prebuild is occupancy-bound.
// R16: two occupancy-NEUTRAL fixes on the R14 base:
//  - bucket_count grid 1024->256 blocks: the final bcnt flush is 600K
//    contended global atomics over 37 lines (~30us serialized tail, by
//    R13's measured ~31B/atomic line-RMW model) -> 4x fewer contributors.
//  - init_kernel FUSED into csr_build: each bucket block writes xsA for its
//    own 256 rows (has dis in LDS); block 0 zeroes both sentinels. One
//    kernel + one dependency bubble deleted. LDS +1KB -> still 2 blocks/CU.
// spmm kernels byte-identical (tripwire: spmm_last 118us / FETCH 376MB).

static constexpr int D = 64;
#define BSHIFT 8
#define BROWS 256               // rows per bucket
#define KP 1024                 // padded bucket count for scans (>= KB=586)
#define TILE 4096               // entries per bucket_scatter block (256 thr x 16)
#define TK 16                   // TILE/256
#define PADSLACK (7 * BROWS)    // max pad growth per bucket (rows pad to x8)
#define FULL_CAP 16384          // full-bucket staging entries (64 KB LDS)
#define COLS_SLACK 8192         // safe over-read slack for spmm col loads

__device__ __forceinline__ float bflo(unsigned v) {
    unsigned u = v << 16;
    return __builtin_bit_cast(float, u);
}
__device__ __forceinline__ float bfhi(unsigned v) {
    unsigned u = v & 0xFFFF0000u;
    return __builtin_bit_cast(float, u);
}
__device__ __forceinline__ unsigned pack_bf16x2(float a, float b) {
    unsigned ua = __builtin_bit_cast(unsigned, a);
    unsigned ub = __builtin_bit_cast(unsigned, b);
    ua += 0x7FFFu + ((ua >> 16) & 1u);   // RNE
    ub += 0x7FFFu + ((ub >> 16) & 1u);
    return (ua >> 16) | (ub & 0xFFFF0000u);
}
// f16 pack/unpack for the x_l recovery arrays (RNE via _Float16 cast).
__device__ __forceinline__ unsigned pack_f16x2(float a, float b) {
    unsigned short ua = __builtin_bit_cast(unsigned short, (_Float16)a);
    unsigned short ub = __builtin_bit_cast(unsigned short, (_Float16)b);
    return (unsigned)ua | ((unsigned)ub << 16);
}
__device__ __forceinline__ float f16lo(unsigned v) {
    return (float)__builtin_bit_cast(_Float16, (unsigned short)(v & 0xFFFFu));
}
__device__ __forceinline__ float f16hi(unsigned v) {
    return (float)__builtin_bit_cast(_Float16, (unsigned short)(v >> 16));
}

// bf16x2 pair accumulate: se += lo, so += hi. Exact f32 adds.
__device__ __forceinline__ void acc_bf2(unsigned u, float& se, float& so) {
    se += bflo(u);
    so += bfhi(u);
}

// ---- Pass 0: per-bucket histogram (LDS only; int4-vectorized edge reads) ----
// R16: launched with 256 blocks (was 1024) to cut the contended global
// atomic flush 4x. Grid-stride body unchanged.
__global__ __launch_bounds__(256) void bucket_count(
        const int* __restrict__ eu, const int* __restrict__ ei,
        int* __restrict__ bcnt, int E, int U) {
    __shared__ int h[KP];
    int tid = threadIdx.x;
#pragma unroll
    for (int k = 0; k < 4; ++k) h[tid + k * 256] = 0;
    __syncthreads();
    int E4 = E >> 2;
    int stride = gridDim.x * blockDim.x;
    int g = blockIdx.x * blockDim.x + tid;
    const int4* eu4 = (const int4*)eu;
    const int4* ei4 = (const int4*)ei;
    for (int e = g; e < E4; e += stride) {
        int4 u = eu4[e];
        int4 it = ei4[e];
        atomicAdd(&h[u.x >> BSHIFT], 1);
        atomicAdd(&h[u.y >> BSHIFT], 1);
        atomicAdd(&h[u.z >> BSHIFT], 1);
        atomicAdd(&h[u.w >> BSHIFT], 1);
        atomicAdd(&h[(U + it.x) >> BSHIFT], 1);
        atomicAdd(&h[(U + it.y) >> BSHIFT], 1);
        atomicAdd(&h[(U + it.z) >> BSHIFT], 1);
        atomicAdd(&h[(U + it.w) >> BSHIFT], 1);
    }
    if (blockIdx.x == 0 && tid < (E - (E4 << 2))) {   // tail (<4 edges)
        int e = (E4 << 2) + tid;
        atomicAdd(&h[eu[e] >> BSHIFT], 1);
        atomicAdd(&h[(U + ei[e]) >> BSHIFT], 1);
    }
    __syncthreads();
#pragma unroll
    for (int k = 0; k < 4; ++k) {
        int v = h[tid + k * 256];
        if (v) atomicAdd(&bcnt[tid + k * 256], v);
    }
}

// ---- Pass 1: scan bucket counts -> bucket bases + global cursors ----
__global__ void bscan(const int* __restrict__ bcnt, int* __restrict__ bbase,
                      int* __restrict__ bcursor, int KB, int twoE) {
    __shared__ int s[KP];
    int tid = threadIdx.x; // 1024 threads, 1 block
    int v = (tid < KB) ? bcnt[tid] : 0;
    s[tid] = v;
    __syncthreads();
    for (int off = 1; off < KP; off <<= 1) {
        int a = (tid >= off) ? s[tid - off] : 0;
        __syncthreads();
        s[tid] += a;
        __syncthreads();
    }
    int ex = s[tid] - v; // exclusive
    if (tid < KB) { bbase[tid] = ex; bcursor[tid] = ex; }
    if (tid == KB) bbase[tid] = twoE;
    if (tid > KB) bcursor[tid] = 0;
}

// ---- Pass 2: scatter entries into bucket-grouped pairs buffer ----
// packed entry: (row & 255) << 18 | col   (col < 2^18)
__global__ __launch_bounds__(256) void bucket_scatter(
        const int* __restrict__ eu, const int* __restrict__ ei,
        int* __restrict__ bcursor, unsigned* __restrict__ pairs,
        int E, int U, int twoE) {
    __shared__ int hist[KP];           // counts -> local running cursor
    __shared__ int sbase[KP];          // tile-local exclusive base
    __shared__ int gbase[KP];          // reserved global base
    __shared__ unsigned staging[TILE];
    __shared__ unsigned short sb[TILE];
    int tid = threadIdx.x;
#pragma unroll
    for (int k = 0; k < 4; ++k) hist[tid + k * 256] = 0;
    __syncthreads();
    int base_e = blockIdx.x * TILE;
    int bk[TK]; unsigned pk[TK];
#pragma unroll
    for (int k = 0; k < TK; ++k) {
        int e = base_e + k * 256 + tid;
        bk[k] = -1;
        if (e < twoE) {
            int r, c;
            if (e < E) { r = eu[e]; c = U + ei[e]; }
            else       { c = eu[e - E]; r = U + ei[e - E]; }
            int b = r >> BSHIFT;
            bk[k] = b;
            pk[k] = ((unsigned)(r & (BROWS - 1)) << 18) | (unsigned)c;
            atomicAdd(&hist[b], 1);
        }
    }
    __syncthreads();
    int cc[4];
#pragma unroll
    for (int k = 0; k < 4; ++k) cc[k] = hist[tid + k * 256];
    for (int off = 1; off < KP; off <<= 1) {
        int a[4];
#pragma unroll
        for (int k = 0; k < 4; ++k) {
            int idx = tid + k * 256;
            a[k] = (idx >= off) ? hist[idx - off] : 0;
        }
        __syncthreads();
#pragma unroll
        for (int k = 0; k < 4; ++k) hist[tid + k * 256] += a[k];
        __syncthreads();
    }
#pragma unroll
    for (int k = 0; k < 4; ++k) {
        int idx = tid + k * 256;
        int e0 = hist[idx] - cc[k];
        sbase[idx] = e0;
        if (cc[k] > 0) gbase[idx] = atomicAdd(&bcursor[idx], cc[k]);
        hist[idx] = e0;     // own-slot overwrite, no cross reads
    }
    __syncthreads();
#pragma unroll
    for (int k = 0; k < TK; ++k) {
        if (bk[k] >= 0) {
            int pos = atomicAdd(&hist[bk[k]], 1);
            staging[pos] = pk[k];
            sb[pos] = (unsigned short)bk[k];
        }
    }
    __syncthreads();
    int tile_n = min(TILE, twoE - base_e);
#pragma unroll
    for (int k = 0; k < TK; ++k) {
        int j = k * 256 + tid;
        if (j < tile_n) {
            int b = sb[j];
            pairs[gbase[b] + (j - sbase[b])] = staging[j];
        }
    }
}

// ---- Pass 3: per-bucket counting sort -> deg/row_ptr/dis/cols + xs init ----
// 256 threads, one thread per row. Padded base = bbase[b] + 1792*b.
// R14 structure: LDS histogram pass over pairs (read 1), full-bucket 64KB
// staging scatter (read 2), coalesced flush.
// R16: init FUSED -- after dis is computed, each block writes the bf16
// pre-scaled xsA rows for its own 256 rows (emb read, coalesced); block 0
// zeroes the sentinel row N in BOTH xs buffers.
__global__ __launch_bounds__(256) void csr_build(
        const unsigned* __restrict__ pairs, const int* __restrict__ bbase,
        int* __restrict__ deg, int* __restrict__ row_ptr,
        float* __restrict__ dis, int* __restrict__ cols,
        const float4* __restrict__ ue4, const float4* __restrict__ ie4,
        uint4* __restrict__ xsA4, uint4* __restrict__ xsB4,
        int U, int N) {
    __shared__ int cnt[BROWS];
    __shared__ int cur[BROWS];
    __shared__ float diss[BROWS];
    __shared__ int lbuf[FULL_CAP];
    int tid = threadIdx.x;
    int b = blockIdx.x;
    int lo = bbase[b], hi = bbase[b + 1];
    int cbase = lo + PADSLACK * b;
    cnt[tid] = 0;
    __syncthreads();
    for (int i = lo + tid; i < hi; i += 256) atomicAdd(&cnt[pairs[i] >> 18], 1);
    __syncthreads();
    int c = cnt[tid];
    int p = (c + 7) & ~7;
    cnt[tid] = p;                        // own-slot overwrite, no cross reads
    __syncthreads();
    for (int off = 1; off < BROWS; off <<= 1) {
        int a = (tid >= off) ? cnt[tid - off] : 0;
        __syncthreads();
        cnt[tid] += a;
        __syncthreads();
    }
    int e = cnt[tid] - p; // exclusive padded offset within bucket
    int r = (b << BSHIFT) + tid;
    float drv = rsqrtf((float)c + 1e-7f);
    diss[tid] = drv;
    if (r < N) {
        deg[r] = c;
        row_ptr[r] = cbase + e;
        dis[r] = drv;
    }
    cur[tid] = e;
    int total = cnt[BROWS - 1];          // padded bucket total (block-uniform)
    __syncthreads();                     // cur[]/diss[] visible
    // ---- fused init: write xsA rows for this bucket (overlaps with the
    // pairs staging below via wave interleave). t = (local row, part).
    for (int t = tid; t < BROWS * 8; t += 256) {
        int rr = (b << BSHIFT) + (t >> 3);
        if (rr < N) {
            float dv = diss[t >> 3];
            int part = t & 7;
            const float4* src = (rr < U)
                ? (ue4 + ((size_t)rr * 16 + part * 2))
                : (ie4 + ((size_t)(rr - U) * 16 + part * 2));
            float4 a0 = src[0];
            float4 a1 = src[1];
            uint4 w;
            w.x = pack_bf16x2(dv * a0.x, dv * a0.y);
            w.y = pack_bf16x2(dv * a0.z, dv * a0.w);
            w.z = pack_bf16x2(dv * a1.x, dv * a1.y);
            w.w = pack_bf16x2(dv * a1.z, dv * a1.w);
            xsA4[(size_t)rr * 8 + part] = w;
        }
    }
    if (b == 0 && tid < 8) {             // sentinel zero-row N, both buffers
        uint4 z = {0u, 0u, 0u, 0u};
        xsA4[(size_t)N * 8 + tid] = z;
        xsB4[(size_t)N * 8 + tid] = z;
    }
    // ---- counting-sort scatter into LDS, then coalesced flush
    if (total <= FULL_CAP) {
        for (int i = lo + tid; i < hi; i += 256) {
            unsigned pe = pairs[i];
            int pos = atomicAdd(&cur[pe >> 18], 1);
            lbuf[pos] = (int)(pe & 0x3FFFFu);
        }
        __syncthreads();
        for (int i = e + c; i < e + p; ++i) lbuf[i] = N;   // sentinel pad
        __syncthreads();
        for (int i = tid; i < total; i += 256)             // coalesced flush
            cols[cbase + i] = lbuf[i];
    } else {
        // fallback: direct global scatter (pathological bucket size)
        for (int i = lo + tid; i < hi; i += 256) {
            unsigned pe = pairs[i];
            int pos = atomicAdd(&cur[pe >> 18], 1);
            cols[cbase + pos] = (int)(pe & 0x3FFFFu);
        }
        __syncthreads();
        for (int i = e + c; i < e + p; ++i) cols[cbase + i] = N;
    }
}

// One wave per row. lane = (n8 = lane>>3 neighbor slot, dp = lane&7 uint4 idx).
// One uint4 load covers 8 neighbor rows per instruction; one ds_bpermute per
// octet broadcasts the 8 cols. Rows padded to x8 with sentinel -> no tail code.
// Phase-split body: all bpermutes, then all gathers (up to 8 in flight), then
// accumulate. Layers 0/1: write xs_next + xh (f16 x_l copy) -- no f32 acc RMW.
__global__ __launch_bounds__(256) void spmm_mid(
        const int* __restrict__ row_ptr, const int* __restrict__ deg,
        const float* __restrict__ dis, const int* __restrict__ cols,
        const unsigned* __restrict__ xs, unsigned* __restrict__ xs_next,
        unsigned* __restrict__ xh, int N) {
    int wid = blockIdx.x * 4 + (threadIdx.x >> 6);
    if (wid >= N) return;
    int lane = threadIdx.x & 63;
    int n8 = lane >> 3;
    int dp = lane & 7;
    int start = row_ptr[wid];
    int cntp = (deg[wid] + 7) & ~7;
    float dr = dis[wid];
    const int* colp = cols + start;
    int vbase = n8 << 2;       // bpermute byte addr component
    int dpo = dp << 2;         // dword offset within row (uint4 = 4 dwords)
    float s0 = 0.f, s1 = 0.f, s2 = 0.f, s3 = 0.f;
    float s4 = 0.f, s5 = 0.f, s6 = 0.f, s7 = 0.f;
    for (int chunk = 0; chunk < cntp; chunk += 64) {
        int cv = colp[chunk + lane];           // over-read OK (slack at end)
        int nq = min(64, cntp - chunk) >> 3;
        nq = __builtin_amdgcn_readfirstlane(nq);   // wave-uniform -> SGPR branch
        int coq[8];
        uint4 vq[8];
#pragma unroll
        for (int q = 0; q < 8; ++q) {
            if (q < nq)
                coq[q] = __builtin_amdgcn_ds_bpermute((q << 5) + vbase, cv);
        }
#pragma unroll
        for (int q = 0; q < 8; ++q) {
            if (q < nq)
                vq[q] = *(const uint4*)(xs + (((unsigned)coq[q]) << 5) + dpo);
        }
#pragma unroll
        for (int q = 0; q < 8; ++q) {
            if (q < nq) {
                acc_bf2(vq[q].x, s0, s1);
                acc_bf2(vq[q].y, s2, s3);
                acc_bf2(vq[q].z, s4, s5);
                acc_bf2(vq[q].w, s6, s7);
            }
        }
    }
#pragma unroll
    for (int m = 8; m < 64; m <<= 1) {
        s0 += __shfl_xor(s0, m); s1 += __shfl_xor(s1, m);
        s2 += __shfl_xor(s2, m); s3 += __shfl_xor(s3, m);
        s4 += __shfl_xor(s4, m); s5 += __shfl_xor(s5, m);
        s6 += __shfl_xor(s6, m); s7 += __shfl_xor(s7, m);
    }
    if (n8 == 0) {
        float x0 = dr * s0, x1 = dr * s1, x2 = dr * s2, x3 = dr * s3;
        float x4 = dr * s4, x5 = dr * s5, x6 = dr * s6, x7 = dr * s7;
        uint4 w;
        w.x = pack_bf16x2(dr * x0, dr * x1);   // xs_next = dr^2 * S
        w.y = pack_bf16x2(dr * x2, dr * x3);
        w.z = pack_bf16x2(dr * x4, dr * x5);
        w.w = pack_bf16x2(dr * x6, dr * x7);
        ((uint4*)xs_next)[(wid << 3) + dp] = w;
        uint4 h;
        h.x = pack_f16x2(x0, x1);              // xh = x_l (f16, for final sum)
        h.y = pack_f16x2(x2, x3);
        h.z = pack_f16x2(x4, x5);
        h.w = pack_f16x2(x6, x7);
        ((uint4*)xh)[(wid << 3) + dp] = h;
    }
}

// Layer 2: gathers from xs2, then out = 0.25*(emb + x1 + x2 + x3).
// x1/x2 come from the f16 recovery arrays; emb re-read from inputs (f32).
__global__ __launch_bounds__(256) void spmm_last(
        const int* __restrict__ row_ptr, const int* __restrict__ deg,
        const float* __restrict__ dis, const int* __restrict__ cols,
        const unsigned* __restrict__ xs,
        const float4* __restrict__ ue4, const float4* __restrict__ ie4,
        const unsigned* __restrict__ xh1, const unsigned* __restrict__ xh2,
        float4* __restrict__ out4, int U, int N) {
    int wid = blockIdx.x * 4 + (threadIdx.x >> 6);
    if (wid >= N) return;
    int lane = threadIdx.x & 63;
    int n8 = lane >> 3;
    int dp = lane & 7;
    int start = row_ptr[wid];
    int cntp = (deg[wid] + 7) & ~7;
    float dr = dis[wid];
    const int* colp = cols + start;
    int vbase = n8 << 2;
    int dpo = dp << 2;
    float s0 = 0.f, s1 = 0.f, s2 = 0.f, s3 = 0.f;
    float s4 = 0.f, s5 = 0.f, s6 = 0.f, s7 = 0.f;
    for (int chunk = 0; chunk < cntp; chunk += 64) {
        int cv = colp[chunk + lane];
        int nq = min(64, cntp - chunk) >> 3;
        nq = __builtin_amdgcn_readfirstlane(nq);
        int coq[8];
        uint4 vq[8];
#pragma unroll
        for (int q = 0; q < 8; ++q) {
            if (q < nq)
                coq[q] = __builtin_amdgcn_ds_bpermute((q << 5) + vbase, cv);
        }
#pragma unroll
        for (int q = 0; q < 8; ++q) {
            if (q < nq)
                vq[q] = *(const uint4*)(xs + (((unsigned)coq[q]) << 5) + dpo);
        }
#pragma unroll
        for (int q = 0; q < 8; ++q) {
            if (q < nq) {
                acc_bf2(vq[q].x, s0, s1);
                acc_bf2(vq[q].y, s2, s3);
                acc_bf2(vq[q].z, s4, s5);
                acc_bf2(vq[q].w, s6, s7);
            }
        }
    }
#pragma unroll
    for (int m = 8; m < 64; m <<= 1) {
        s0 += __shfl_xor(s0, m); s1 += __shfl_xor(s1, m);
        s2 += __shfl_xor(s2, m); s3 += __shfl_xor(s3, m);
        s4 += __shfl_xor(s4, m); s5 += __shfl_xor(s5, m);
        s6 += __shfl_xor(s6, m); s7 += __shfl_xor(s7, m);
    }
    if (n8 == 0) {
        float x30 = dr * s0, x31 = dr * s1, x32 = dr * s2, x33 = dr * s3;
        float x34 = dr * s4, x35 = dr * s5, x36 = dr * s6, x37 = dr * s7;
        const float4* ep = (wid < U) ? (ue4 + (size_t)wid * 16)
                                     : (ie4 + (size_t)(wid - U) * 16);
        float4 e0 = ep[2 * dp];
        float4 e1 = ep[2 * dp + 1];
        uint4 h1 = ((const uint4*)xh1)[(wid << 3) + dp];
        uint4 h2 = ((const uint4*)xh2)[(wid << 3) + dp];
        float4 o0, o1;
        o0.x = 0.25f * (e0.x + f16lo(h1.x) + f16lo(h2.x) + x30);
        o0.y = 0.25f * (e0.y + f16hi(h1.x) + f16hi(h2.x) + x31);
        o0.z = 0.25f * (e0.z + f16lo(h1.y) + f16lo(h2.y) + x32);
        o0.w = 0.25f * (e0.w + f16hi(h1.y) + f16hi(h2.y) + x33);
        o1.x = 0.25f * (e1.x + f16lo(h1.z) + f16lo(h2.z) + x34);
        o1.y = 0.25f * (e1.y + f16hi(h1.z) + f16hi(h2.z) + x35);
        o1.z = 0.25f * (e1.z + f16lo(h1.w) + f16lo(h2.w) + x36);
        o1.w = 0.25f * (e1.w + f16hi(h1.w) + f16hi(h2.w) + x37);
        int oo = (wid << 4) + (dp << 1);
        out4[oo] = o0;
        out4[oo + 1] = o1;
    }
}

extern "C" void kernel_launch(void* const* d_in, const int* in_sizes, int n_in,
                              void* d_out, int out_size, void* d_ws, size_t ws_size,
                              hipStream_t stream) {
    const float* ue = (const float*)d_in[0];
    const float* ie = (const float*)d_in[1];
    const int* eu = (const int*)d_in[2];
    const int* ei = (const int*)d_in[3];
    const int U = in_sizes[0] / D; // 100001
    const int I = in_sizes[1] / D; // 50001
    const int N = U + I;           // 150002
    const int E = in_sizes[2];     // 4,000,000
    const int twoE = 2 * E;
    const int KB = (N + BROWS - 1) / BROWS; // 586
    float* out = (float*)d_out;

    char* ws = (char*)d_ws;
    auto alloc = [&](size_t bytes) {
        char* p = ws;
        ws += (bytes + 255) & ~(size_t)255;
        return p;
    };
    int* deg = (int*)alloc((size_t)N * 4);
    int* row_ptr = (int*)alloc((size_t)N * 4);
    float* dis = (float*)alloc((size_t)N * 4);
    int* bcnt = (int*)alloc(KP * 4);
    int* bbase = (int*)alloc((KP + 1) * 4);
    int* bcursor = (int*)alloc(KP * 4);
    int* cols = (int*)alloc(((size_t)twoE + (size_t)PADSLACK * (KB + 1) + COLS_SLACK) * 4);
    unsigned* pairs = (unsigned*)alloc((size_t)twoE * 4);       // 32 MB
    unsigned* xsA = (unsigned*)alloc(((size_t)N + 1) * 32 * 4); // bf16x2, +sentinel row
    unsigned* xsB = (unsigned*)alloc(((size_t)N + 1) * 32 * 4);
    // xh1 aliases `pairs` (dead after csr_build; 19.2MB <= 32MB). xh2 fresh.
    unsigned* xh1 = pairs;
    unsigned* xh2 = (unsigned*)alloc((size_t)N * 32 * 4);

    hipMemsetAsync(bcnt, 0, KP * 4, stream);
    bucket_count<<<256, 256, 0, stream>>>(eu, ei, bcnt, E, U);
    bscan<<<1, KP, 0, stream>>>(bcnt, bbase, bcursor, KB, twoE);
    bucket_scatter<<<(twoE + TILE - 1) / TILE, 256, 0, stream>>>(
        eu, ei, bcursor, pairs, E, U, twoE);
    csr_build<<<KB, BROWS, 0, stream>>>(
        pairs, bbase, deg, row_ptr, dis, cols,
        (const float4*)ue, (const float4*)ie,
        (uint4*)xsA, (uint4*)xsB, U, N);

    int nblocks = (N + 3) / 4;
    // layer 0: xs0(A) -> xs1(B), xh1 = x1 (f16)
    spmm_mid<<<nblocks, 256, 0, stream>>>(
        row_ptr, deg, dis, cols, xsA, xsB, xh1, N);
    // layer 1: xs1(B) -> xs2(A; A is dead, sentinel intact), xh2 = x2 (f16)
    spmm_mid<<<nblocks, 256, 0, stream>>>(
        row_ptr, deg, dis, cols, xsB, xsA, xh2, N);
    // layer 2: gather xs2(A); out = 0.25*(emb + x1 + x2 + x3)
    spmm_last<<<nblocks, 256, 0, stream>>>(
        row_ptr, deg, dis, cols, xsA,
        (const float4*)ue, (const float4*)ie, xh1, xh2, (float4*)out, U, N);
}

// Round 11
// 579.589 us; speedup vs baseline: 1.0743x; 1.0297x over previous
//
#include <hip/hip_runtime.h>

// LightGCN: N=U+I nodes, D=64 features, E edges (symmetrized to 2E directed).
// CSR built per call via bucket sort (256-row buckets). Rows PADDED to
// multiples of 8 with sentinel zero-row N -> branch-free SpMM.
// x stored pre-scaled: xs[c] = dis[c]*x[c] (bf16x2 packed, row = 128B):
// S = sum xs[c]; x_new = dr*S; xs_next = dr^2*S.
// R8: NO fdot2_f32_bf16 (wrong results on gfx950).
// R9 (REVERTED): row-per-octet spmm. R7 phase-split wave-per-row stays.
// R10: spmm BYTES-bound at ~3.5 TB/s TCC plateau; f32 acc RMW eliminated.
// R11 (REVERTED): range-sorted cols -> no orderable locality.
// R12/R13 (REVERTED): global-atomic histogram: scattered device-scope
// atomics ~31B line-RMW each at the cross-XCD coherence point.
// R14: 587.6us (best). TILE-4096 staged scatter; csr_build 64KB staging.
// R15 (REVERTED): byte-saving via occupancy loss -> +35us.
// R16 (REVERTED): grid 1024->256 starved the 32MB edge-read of TLP; init
// fusion lengthened csr_build critical path. Net +9us. Lesson: don't bundle.
// R17: R14-exact base + ONE isolated fix: bucket_count flushes into 64
// PRIVATE histogram slices (blockIdx&63; 16 blocks/slice -> atomics spread
// over 2368 lines instead of 37, ~250 RMW/line) keeping 1024 blocks of read
// TLP; bscan folds the slices (256KB, lane-coalesced, ~2us).
// spmm kernels byte-identical (tripwire: spmm_last 118us / FETCH 376MB).

static constexpr int D = 64;
#define BSHIFT 8
#define BROWS 256               // rows per bucket
#define KP 1024                 // padded bucket count for scans (>= KB=586)
#define NSL 64                  // private histogram slices for bucket_count
#define TILE 4096               // entries per bucket_scatter block (256 thr x 16)
#define TK 16                   // TILE/256
#define PADSLACK (7 * BROWS)    // max pad growth per bucket (rows pad to x8)
#define FULL_CAP 16384          // full-bucket staging entries (64 KB LDS)
#define COLS_SLACK 8192         // safe over-read slack for spmm col loads

__device__ __forceinline__ float bflo(unsigned v) {
    unsigned u = v << 16;
    return __builtin_bit_cast(float, u);
}
__device__ __forceinline__ float bfhi(unsigned v) {
    unsigned u = v & 0xFFFF0000u;
    return __builtin_bit_cast(float, u);
}
__device__ __forceinline__ unsigned pack_bf16x2(float a, float b) {
    unsigned ua = __builtin_bit_cast(unsigned, a);
    unsigned ub = __builtin_bit_cast(unsigned, b);
    ua += 0x7FFFu + ((ua >> 16) & 1u);   // RNE
    ub += 0x7FFFu + ((ub >> 16) & 1u);
    return (ua >> 16) | (ub & 0xFFFF0000u);
}
// f16 pack/unpack for the x_l recovery arrays (RNE via _Float16 cast).
__device__ __forceinline__ unsigned pack_f16x2(float a, float b) {
    unsigned short ua = __builtin_bit_cast(unsigned short, (_Float16)a);
    unsigned short ub = __builtin_bit_cast(unsigned short, (_Float16)b);
    return (unsigned)ua | ((unsigned)ub << 16);
}
__device__ __forceinline__ float f16lo(unsigned v) {
    return (float)__builtin_bit_cast(_Float16, (unsigned short)(v & 0xFFFFu));
}
__device__ __forceinline__ float f16hi(unsigned v) {
    return (float)__builtin_bit_cast(_Float16, (unsigned short)(v >> 16));
}

// bf16x2 pair accumulate: se += lo, so += hi. Exact f32 adds.
__device__ __forceinline__ void acc_bf2(unsigned u, float& se, float& so) {
    se += bflo(u);
    so += bfhi(u);
}

// ---- Pass 0: per-bucket histogram (LDS only; int4-vectorized edge reads) ----
// R17: flush into slice (blockIdx & 63) of bcnt_sl -- spreads the contended
// atomic tail over 64x more lines while keeping 1024 blocks of read TLP.
__global__ __launch_bounds__(256) void bucket_count(
        const int* __restrict__ eu, const int* __restrict__ ei,
        int* __restrict__ bcnt_sl, int E, int U) {
    __shared__ int h[KP];
    int tid = threadIdx.x;
#pragma unroll
    for (int k = 0; k < 4; ++k) h[tid + k * 256] = 0;
    __syncthreads();
    int E4 = E >> 2;
    int stride = gridDim.x * blockDim.x;
    int g = blockIdx.x * blockDim.x + tid;
    const int4* eu4 = (const int4*)eu;
    const int4* ei4 = (const int4*)ei;
    for (int e = g; e < E4; e += stride) {
        int4 u = eu4[e];
        int4 it = ei4[e];
        atomicAdd(&h[u.x >> BSHIFT], 1);
        atomicAdd(&h[u.y >> BSHIFT], 1);
        atomicAdd(&h[u.z >> BSHIFT], 1);
        atomicAdd(&h[u.w >> BSHIFT], 1);
        atomicAdd(&h[(U + it.x) >> BSHIFT], 1);
        atomicAdd(&h[(U + it.y) >> BSHIFT], 1);
        atomicAdd(&h[(U + it.z) >> BSHIFT], 1);
        atomicAdd(&h[(U + it.w) >> BSHIFT], 1);
    }
    if (blockIdx.x == 0 && tid < (E - (E4 << 2))) {   // tail (<4 edges)
        int e = (E4 << 2) + tid;
        atomicAdd(&h[eu[e] >> BSHIFT], 1);
        atomicAdd(&h[(U + ei[e]) >> BSHIFT], 1);
    }
    __syncthreads();
    int sl = (blockIdx.x & (NSL - 1)) * KP;
#pragma unroll
    for (int k = 0; k < 4; ++k) {
        int idx = tid + k * 256;
        int v = h[idx];
        if (v) atomicAdd(&bcnt_sl[sl + idx], v);
    }
}

// ---- Pass 1: fold slices + scan -> bucket bases + global cursors ----
__global__ void bscan(const int* __restrict__ bcnt_sl, int* __restrict__ bbase,
                      int* __restrict__ bcursor, int KB, int twoE) {
    __shared__ int s[KP];
    int tid = threadIdx.x; // 1024 threads, 1 block
    int v = 0;
    if (tid < KB) {
        for (int sl = 0; sl < NSL; ++sl)   // lane-coalesced (consecutive tid)
            v += bcnt_sl[sl * KP + tid];
    }
    s[tid] = v;
    __syncthreads();
    for (int off = 1; off < KP; off <<= 1) {
        int a = (tid >= off) ? s[tid - off] : 0;
        __syncthreads();
        s[tid] += a;
        __syncthreads();
    }
    int ex = s[tid] - v; // exclusive
    if (tid < KB) { bbase[tid] = ex; bcursor[tid] = ex; }
    if (tid == KB) bbase[tid] = twoE;
    if (tid > KB) bcursor[tid] = 0;
}

// ---- Pass 2: scatter entries into bucket-grouped pairs buffer ----
// packed entry: (row & 255) << 18 | col   (col < 2^18)
__global__ __launch_bounds__(256) void bucket_scatter(
        const int* __restrict__ eu, const int* __restrict__ ei,
        int* __restrict__ bcursor, unsigned* __restrict__ pairs,
        int E, int U, int twoE) {
    __shared__ int hist[KP];           // counts -> local running cursor
    __shared__ int sbase[KP];          // tile-local exclusive base
    __shared__ int gbase[KP];          // reserved global base
    __shared__ unsigned staging[TILE];
    __shared__ unsigned short sb[TILE];
    int tid = threadIdx.x;
#pragma unroll
    for (int k = 0; k < 4; ++k) hist[tid + k * 256] = 0;
    __syncthreads();
    int base_e = blockIdx.x * TILE;
    int bk[TK]; unsigned pk[TK];
#pragma unroll
    for (int k = 0; k < TK; ++k) {
        int e = base_e + k * 256 + tid;
        bk[k] = -1;
        if (e < twoE) {
            int r, c;
            if (e < E) { r = eu[e]; c = U + ei[e]; }
            else       { c = eu[e - E]; r = U + ei[e - E]; }
            int b = r >> BSHIFT;
            bk[k] = b;
            pk[k] = ((unsigned)(r & (BROWS - 1)) << 18) | (unsigned)c;
            atomicAdd(&hist[b], 1);
        }
    }
    __syncthreads();
    int cc[4];
#pragma unroll
    for (int k = 0; k < 4; ++k) cc[k] = hist[tid + k * 256];
    for (int off = 1; off < KP; off <<= 1) {
        int a[4];
#pragma unroll
        for (int k = 0; k < 4; ++k) {
            int idx = tid + k * 256;
            a[k] = (idx >= off) ? hist[idx - off] : 0;
        }
        __syncthreads();
#pragma unroll
        for (int k = 0; k < 4; ++k) hist[tid + k * 256] += a[k];
        __syncthreads();
    }
#pragma unroll
    for (int k = 0; k < 4; ++k) {
        int idx = tid + k * 256;
        int e0 = hist[idx] - cc[k];
        sbase[idx] = e0;
        if (cc[k] > 0) gbase[idx] = atomicAdd(&bcursor[idx], cc[k]);
        hist[idx] = e0;     // own-slot overwrite, no cross reads
    }
    __syncthreads();
#pragma unroll
    for (int k = 0; k < TK; ++k) {
        if (bk[k] >= 0) {
            int pos = atomicAdd(&hist[bk[k]], 1);
            staging[pos] = pk[k];
            sb[pos] = (unsigned short)bk[k];
        }
    }
    __syncthreads();
    int tile_n = min(TILE, twoE - base_e);
#pragma unroll
    for (int k = 0; k < TK; ++k) {
        int j = k * 256 + tid;
        if (j < tile_n) {
            int b = sb[j];
            pairs[gbase[b] + (j - sbase[b])] = staging[j];
        }
    }
}

// ---- Pass 3: per-bucket counting sort -> deg/row_ptr/dis/cols ----
// 256 threads, one thread per row. Padded base = bbase[b] + 1792*b.
// R14: LDS histogram pass over pairs (read 1; yields deg/row_ptr/dis), then
// FULL bucket staged in 64KB LDS in one scatter pass (read 2), coalesced
// flush. Fallback: direct global scatter.
__global__ __launch_bounds__(256) void csr_build(
        const unsigned* __restrict__ pairs, const int* __restrict__ bbase,
        int* __restrict__ deg, int* __restrict__ row_ptr,
        float* __restrict__ dis, int* __restrict__ cols, int N) {
    __shared__ int cnt[BROWS];
    __shared__ int cur[BROWS];
    __shared__ int lbuf[FULL_CAP];
    int tid = threadIdx.x;
    int b = blockIdx.x;
    int lo = bbase[b], hi = bbase[b + 1];
    int cbase = lo + PADSLACK * b;
    cnt[tid] = 0;
    __syncthreads();
    for (int i = lo + tid; i < hi; i += 256) atomicAdd(&cnt[pairs[i] >> 18], 1);
    __syncthreads();
    int c = cnt[tid];
    int p = (c + 7) & ~7;
    cnt[tid] = p;                        // own-slot overwrite, no cross reads
    __syncthreads();
    for (int off = 1; off < BROWS; off <<= 1) {
        int a = (tid >= off) ? cnt[tid - off] : 0;
        __syncthreads();
        cnt[tid] += a;
        __syncthreads();
    }
    int e = cnt[tid] - p; // exclusive padded offset within bucket
    int r = (b << BSHIFT) + tid;
    if (r < N) {
        deg[r] = c;
        row_ptr[r] = cbase + e;
        dis[r] = rsqrtf((float)c + 1e-7f);
    }
    cur[tid] = e;
    int total = cnt[BROWS - 1];          // padded bucket total (block-uniform)
    __syncthreads();                     // cur[] visible before scatter
    if (total <= FULL_CAP) {
        for (int i = lo + tid; i < hi; i += 256) {
            unsigned pe = pairs[i];
            int pos = atomicAdd(&cur[pe >> 18], 1);
            lbuf[pos] = (int)(pe & 0x3FFFFu);
        }
        __syncthreads();
        for (int i = e + c; i < e + p; ++i) lbuf[i] = N;   // sentinel pad
        __syncthreads();
        for (int i = tid; i < total; i += 256)             // coalesced flush
            cols[cbase + i] = lbuf[i];
    } else {
        // fallback: direct global scatter (pathological bucket size)
        for (int i = lo + tid; i < hi; i += 256) {
            unsigned pe = pairs[i];
            int pos = atomicAdd(&cur[pe >> 18], 1);
            cols[cbase + pos] = (int)(pe & 0x3FFFFu);
        }
        __syncthreads();
        for (int i = e + c; i < e + p; ++i) cols[cbase + i] = N;
    }
}

// init: writes xs0 (bf16 pre-scaled) + sentinel zero-rows of BOTH xs buffers.
// NO acc write (out is produced once, by spmm_last).
__global__ __launch_bounds__(256) void init_kernel(
        const float4* __restrict__ ue4, const float4* __restrict__ ie4,
        const float* __restrict__ dis,
        uint4* __restrict__ xsA4, uint4* __restrict__ xsB4,
        int U8, int N8) {
    int t = blockIdx.x * blockDim.x + threadIdx.x;
    if (t >= N8 + 8) return;
    if (t >= N8) {                        // sentinel zero-row N (both buffers)
        uint4 z = {0u, 0u, 0u, 0u};
        xsA4[t] = z;
        xsB4[t] = z;
        return;
    }
    float dv = dis[t >> 3];
    const float4* src = (t < U8) ? (ue4 + 2 * t) : (ie4 + 2 * (t - U8));
    float4 a0 = src[0];
    float4 a1 = src[1];
    uint4 w;
    w.x = pack_bf16x2(dv * a0.x, dv * a0.y);
    w.y = pack_bf16x2(dv * a0.z, dv * a0.w);
    w.z = pack_bf16x2(dv * a1.x, dv * a1.y);
    w.w = pack_bf16x2(dv * a1.z, dv * a1.w);
    xsA4[t] = w;
}

// One wave per row. lane = (n8 = lane>>3 neighbor slot, dp = lane&7 uint4 idx).
// One uint4 load covers 8 neighbor rows per instruction; one ds_bpermute per
// octet broadcasts the 8 cols. Rows padded to x8 with sentinel -> no tail code.
// Phase-split body: all bpermutes, then all gathers (up to 8 in flight), then
// accumulate. Layers 0/1: write xs_next + xh (f16 x_l copy) -- no f32 acc RMW.
__global__ __launch_bounds__(256) void spmm_mid(
        const int* __restrict__ row_ptr, const int* __restrict__ deg,
        const float* __restrict__ dis, const int* __restrict__ cols,
        const unsigned* __restrict__ xs, unsigned* __restrict__ xs_next,
        unsigned* __restrict__ xh, int N) {
    int wid = blockIdx.x * 4 + (threadIdx.x >> 6);
    if (wid >= N) return;
    int lane = threadIdx.x & 63;
    int n8 = lane >> 3;
    int dp = lane & 7;
    int start = row_ptr[wid];
    int cntp = (deg[wid] + 7) & ~7;
    float dr = dis[wid];
    const int* colp = cols + start;
    int vbase = n8 << 2;       // bpermute byte addr component
    int dpo = dp << 2;         // dword offset within row (uint4 = 4 dwords)
    float s0 = 0.f, s1 = 0.f, s2 = 0.f, s3 = 0.f;
    float s4 = 0.f, s5 = 0.f, s6 = 0.f, s7 = 0.f;
    for (int chunk = 0; chunk < cntp; chunk += 64) {
        int cv = colp[chunk + lane];           // over-read OK (slack at end)
        int nq = min(64, cntp - chunk) >> 3;
        nq = __builtin_amdgcn_readfirstlane(nq);   // wave-uniform -> SGPR branch
        int coq[8];
        uint4 vq[8];
#pragma unroll
        for (int q = 0; q < 8; ++q) {
            if (q < nq)
                coq[q] = __builtin_amdgcn_ds_bpermute((q << 5) + vbase, cv);
        }
#pragma unroll
        for (int q = 0; q < 8; ++q) {
            if (q < nq)
                vq[q] = *(const uint4*)(xs + (((unsigned)coq[q]) << 5) + dpo);
        }
#pragma unroll
        for (int q = 0; q < 8; ++q) {
            if (q < nq) {
                acc_bf2(vq[q].x, s0, s1);
                acc_bf2(vq[q].y, s2, s3);
                acc_bf2(vq[q].z, s4, s5);
                acc_bf2(vq[q].w, s6, s7);
            }
        }
    }
#pragma unroll
    for (int m = 8; m < 64; m <<= 1) {
        s0 += __shfl_xor(s0, m); s1 += __shfl_xor(s1, m);
        s2 += __shfl_xor(s2, m); s3 += __shfl_xor(s3, m);
        s4 += __shfl_xor(s4, m); s5 += __shfl_xor(s5, m);
        s6 += __shfl_xor(s6, m); s7 += __shfl_xor(s7, m);
    }
    if (n8 == 0) {
        float x0 = dr * s0, x1 = dr * s1, x2 = dr * s2, x3 = dr * s3;
        float x4 = dr * s4, x5 = dr * s5, x6 = dr * s6, x7 = dr * s7;
        uint4 w;
        w.x = pack_bf16x2(dr * x0, dr * x1);   // xs_next = dr^2 * S
        w.y = pack_bf16x2(dr * x2, dr * x3);
        w.z = pack_bf16x2(dr * x4, dr * x5);
        w.w = pack_bf16x2(dr * x6, dr * x7);
        ((uint4*)xs_next)[(wid << 3) + dp] = w;
        uint4 h;
        h.x = pack_f16x2(x0, x1);              // xh = x_l (f16, for final sum)
        h.y = pack_f16x2(x2, x3);
        h.z = pack_f16x2(x4, x5);
        h.w = pack_f16x2(x6, x7);
        ((uint4*)xh)[(wid << 3) + dp] = h;
    }
}

// Layer 2: gathers from xs2, then out = 0.25*(emb + x1 + x2 + x3).
// x1/x2 come from the f16 recovery arrays; emb re-read from inputs (f32).
__global__ __launch_bounds__(256) void spmm_last(
        const int* __restrict__ row_ptr, const int* __restrict__ deg,
        const float* __restrict__ dis, const int* __restrict__ cols,
        const unsigned* __restrict__ xs,
        const float4* __restrict__ ue4, const float4* __restrict__ ie4,
        const unsigned* __restrict__ xh1, const unsigned* __restrict__ xh2,
        float4* __restrict__ out4, int U, int N) {
    int wid = blockIdx.x * 4 + (threadIdx.x >> 6);
    if (wid >= N) return;
    int lane = threadIdx.x & 63;
    int n8 = lane >> 3;
    int dp = lane & 7;
    int start = row_ptr[wid];
    int cntp = (deg[wid] + 7) & ~7;
    float dr = dis[wid];
    const int* colp = cols + start;
    int vbase = n8 << 2;
    int dpo = dp << 2;
    float s0 = 0.f, s1 = 0.f, s2 = 0.f, s3 = 0.f;
    float s4 = 0.f, s5 = 0.f, s6 = 0.f, s7 = 0.f;
    for (int chunk = 0; chunk < cntp; chunk += 64) {
        int cv = colp[chunk + lane];
        int nq = min(64, cntp - chunk) >> 3;
        nq = __builtin_amdgcn_readfirstlane(nq);
        int coq[8];
        uint4 vq[8];
#pragma unroll
        for (int q = 0; q < 8; ++q) {
            if (q < nq)
                coq[q] = __builtin_amdgcn_ds_bpermute((q << 5) + vbase, cv);
        }
#pragma unroll
        for (int q = 0; q < 8; ++q) {
            if (q < nq)
                vq[q] = *(const uint4*)(xs + (((unsigned)coq[q]) << 5) + dpo);
        }
#pragma unroll
        for (int q = 0; q < 8; ++q) {
            if (q < nq) {
                acc_bf2(vq[q].x, s0, s1);
                acc_bf2(vq[q].y, s2, s3);
                acc_bf2(vq[q].z, s4, s5);
                acc_bf2(vq[q].w, s6, s7);
            }
        }
    }
#pragma unroll
    for (int m = 8; m < 64; m <<= 1) {
        s0 += __shfl_xor(s0, m); s1 += __shfl_xor(s1, m);
        s2 += __shfl_xor(s2, m); s3 += __shfl_xor(s3, m);
        s4 += __shfl_xor(s4, m); s5 += __shfl_xor(s5, m);
        s6 += __shfl_xor(s6, m); s7 += __shfl_xor(s7, m);
    }
    if (n8 == 0) {
        float x30 = dr * s0, x31 = dr * s1, x32 = dr * s2, x33 = dr * s3;
        float x34 = dr * s4, x35 = dr * s5, x36 = dr * s6, x37 = dr * s7;
        const float4* ep = (wid < U) ? (ue4 + (size_t)wid * 16)
                                     : (ie4 + (size_t)(wid - U) * 16);
        float4 e0 = ep[2 * dp];
        float4 e1 = ep[2 * dp + 1];
        uint4 h1 = ((const uint4*)xh1)[(wid << 3) + dp];
        uint4 h2 = ((const uint4*)xh2)[(wid << 3) + dp];
        float4 o0, o1;
        o0.x = 0.25f * (e0.x + f16lo(h1.x) + f16lo(h2.x) + x30);
        o0.y = 0.25f * (e0.y + f16hi(h1.x) + f16hi(h2.x) + x31);
        o0.z = 0.25f * (e0.z + f16lo(h1.y) + f16lo(h2.y) + x32);
        o0.w = 0.25f * (e0.w + f16hi(h1.y) + f16hi(h2.y) + x33);
        o1.x = 0.25f * (e1.x + f16lo(h1.z) + f16lo(h2.z) + x34);
        o1.y = 0.25f * (e1.y + f16hi(h1.z) + f16hi(h2.z) + x35);
        o1.z = 0.25f * (e1.z + f16lo(h1.w) + f16lo(h2.w) + x36);
        o1.w = 0.25f * (e1.w + f16hi(h1.w) + f16hi(h2.w) + x37);
        int oo = (wid << 4) + (dp << 1);
        out4[oo] = o0;
        out4[oo + 1] = o1;
    }
}

extern "C" void kernel_launch(void* const* d_in, const int* in_sizes, int n_in,
                              void* d_out, int out_size, void* d_ws, size_t ws_size,
                              hipStream_t stream) {
    const float* ue = (const float*)d_in[0];
    const float* ie = (const float*)d_in[1];
    const int* eu = (const int*)d_in[2];
    const int* ei = (const int*)d_in[3];
    const int U = in_sizes[0] / D; // 100001
    const int I = in_sizes[1] / D; // 50001
    const int N = U + I;           // 150002
    const int E = in_sizes[2];     // 4,000,000
    const int twoE = 2 * E;
    const int KB = (N + BROWS - 1) / BROWS; // 586
    float* out = (float*)d_out;

    char* ws = (char*)d_ws;
    auto alloc = [&](size_t bytes) {
        char* p = ws;
        ws += (bytes + 255) & ~(size_t)255;
        return p;
    };
    int* deg = (int*)alloc((size_t)N * 4);
    int* row_ptr = (int*)alloc((size_t)N * 4);
    float* dis = (float*)alloc((size_t)N * 4);
    int* bcnt_sl = (int*)alloc((size_t)NSL * KP * 4);   // 256 KB slices
    int* bbase = (int*)alloc((KP + 1) * 4);
    int* bcursor = (int*)alloc(KP * 4);
    int* cols = (int*)alloc(((size_t)twoE + (size_t)PADSLACK * (KB + 1) + COLS_SLACK) * 4);
    unsigned* pairs = (unsigned*)alloc((size_t)twoE * 4);       // 32 MB
    unsigned* xsA = (unsigned*)alloc(((size_t)N + 1) * 32 * 4); // bf16x2, +sentinel row
    unsigned* xsB = (unsigned*)alloc(((size_t)N + 1) * 32 * 4);
    // xh1 aliases `pairs` (dead after csr_build; 19.2MB <= 32MB). xh2 fresh.
    unsigned* xh1 = pairs;
    unsigned* xh2 = (unsigned*)alloc((size_t)N * 32 * 4);

    hipMemsetAsync(bcnt_sl, 0, (size_t)NSL * KP * 4, stream);
    bucket_count<<<1024, 256, 0, stream>>>(eu, ei, bcnt_sl, E, U);
    bscan<<<1, KP, 0, stream>>>(bcnt_sl, bbase, bcursor, KB, twoE);
    bucket_scatter<<<(twoE + TILE - 1) / TILE, 256, 0, stream>>>(
        eu, ei, bcursor, pairs, E, U, twoE);
    csr_build<<<KB, BROWS, 0, stream>>>(pairs, bbase, deg, row_ptr, dis, cols, N);

    int N8 = N * 8, U8 = U * 8;
    init_kernel<<<(N8 + 8 + 255) / 256, 256, 0, stream>>>(
        (const float4*)ue, (const float4*)ie, dis,
        (uint4*)xsA, (uint4*)xsB, U8, N8);

    int nblocks = (N + 3) / 4;
    // layer 0: xs0(A) -> xs1(B), xh1 = x1 (f16)
    spmm_mid<<<nblocks, 256, 0, stream>>>(
        row_ptr, deg, dis, cols, xsA, xsB, xh1, N);
    // layer 1: xs1(B) -> xs2(A; A is dead, sentinel intact), xh2 = x2 (f16)
    spmm_mid<<<nblocks, 256, 0, stream>>>(
        row_ptr, deg, dis, cols, xsB, xsA, xh2, N);
    // layer 2: gather xs2(A); out = 0.25*(emb + x1 + x2 + x3)
    spmm_last<<<nblocks, 256, 0, stream>>>(
        row_ptr, deg, dis, cols, xsA,
        (const float4*)ue, (const float4*)ie, xh1, xh2, (float4*)out, U, N);
}